// Round 1
// baseline (269.569 us; speedup 1.0000x reference)
//
#include <hip/hip_runtime.h>
#include <hip/hip_bf16.h>

// Problem constants (fixed by setup_inputs): N=32, C=3, H=W=512, A=512,
// SCALE=1 -> out_size=out_sizey=512, ITERS=5, thr0 = 4*512/512 = 4.0f.
#define AN 512     // attention length / out sizes
#define NB 32      // batch
#define HW 512

// ---------------------------------------------------------------------------
// Kernel 1: water-fill + inverse-CDF coords. One block per sample n.
// 512 threads; ax/ay element per thread; reductions via LDS tree;
// cumsum sequential (single thread) to mirror np.cumsum ordering;
// binary search = bisect_left (numpy searchsorted side='left').
// Outputs gx[n][wo], gy[n][ho] in [-1,1] to workspace.
// ---------------------------------------------------------------------------
__global__ __launch_bounds__(512) void waterfill_coords_kernel(
    const float* __restrict__ attx, const float* __restrict__ atty,
    float* __restrict__ gx, float* __restrict__ gy)
{
    __shared__ float axs[AN], ays[AN], csx[AN], csy[AN], redx[AN], redy[AN];
    const int n = blockIdx.x;
    const int t = threadIdx.x;

    float ax = attx[n * AN + t] * 512.0f;   // attx * out_size
    float ay = atty[n * AN + t] * 512.0f;   // atty * out_sizey

    for (int j = 0; j < 5; ++j) {
        // --- max reduction of ax, ay ---
        redx[t] = ax; redy[t] = ay;
        __syncthreads();
        for (int s = 256; s > 0; s >>= 1) {
            if (t < s) {
                redx[t] = fmaxf(redx[t], redx[t + s]);
                redy[t] = fmaxf(redy[t], redy[t + s]);
            }
            __syncthreads();
        }
        float thr = fminf(redx[0], redy[0]);
        if (j == 0) thr = fminf(thr, 4.0f);   // thr0
        __syncthreads();   // everyone read redx[0]/redy[0] before reuse

        ax = fminf(ax, thr);
        ay = fminf(ay, thr);

        // --- sum reduction of clamped ax, ay ---
        redx[t] = ax; redy[t] = ay;
        __syncthreads();
        for (int s = 256; s > 0; s >>= 1) {
            if (t < s) {
                redx[t] = redx[t] + redx[t + s];
                redy[t] = redy[t] + redy[t + s];
            }
            __syncthreads();
        }
        float corx = (512.0f - redx[0]) / 512.0f;
        float cory = (512.0f - redy[0]) / 512.0f;
        __syncthreads();   // everyone read sums before scratch reuse
        ax += corx;
        ay += cory;
    }

    if (t == 0) { ax = 1.0f; ay = 1.0f; }   // ax.at[:,0].set(1.0)
    axs[t] = ax; ays[t] = ay;
    __syncthreads();

    // sequential cumsum (matches numpy's left-to-right accumulation)
    if (t == 0) {
        float run = 0.0f;
        for (int i = 0; i < AN; ++i) { run += axs[i]; csx[i] = run; }
    }
    if (t == 64) {   // different wave -> runs concurrently with t==0 loop
        float run = 0.0f;
        for (int i = 0; i < AN; ++i) { run += ays[i]; csy[i] = run; }
    }
    __syncthreads();

    // --- coords from (axs, csx) -> gy (height coords) ---
    {
        float step = csx[AN - 1] / 512.0f;
        float tv = (float)(t + 1) * step;
        int lo = 0, hi = AN;
        while (lo < hi) {               // bisect_left
            int mid = (lo + hi) >> 1;
            if (csx[mid] < tv) lo = mid + 1; else hi = mid;
        }
        int j = lo > (AN - 1) ? (AN - 1) : lo;
        float prev = (j > 0) ? csx[j - 1] : 0.0f;
        float frac = (tv - prev) / fmaxf(axs[j], 1e-12f);
        gy[n * AN + t] = ((float)j + frac) / 512.0f * 2.0f - 1.0f;
    }
    // --- coords from (ays, csy) -> gx (width coords) ---
    {
        float step = csy[AN - 1] / 512.0f;
        float tv = (float)(t + 1) * step;
        int lo = 0, hi = AN;
        while (lo < hi) {
            int mid = (lo + hi) >> 1;
            if (csy[mid] < tv) lo = mid + 1; else hi = mid;
        }
        int j = lo > (AN - 1) ? (AN - 1) : lo;
        float prev = (j > 0) ? csy[j - 1] : 0.0f;
        float frac = (tv - prev) / fmaxf(ays[j], 1e-12f);
        gx[n * AN + t] = ((float)j + frac) / 512.0f * 2.0f - 1.0f;
    }
}

// ---------------------------------------------------------------------------
// Kernel 2: bilinear grid-sample (zeros padding, align_corners=False) + grid
// materialization. Coordinates are separable: x from gx[n][wo], y from
// gy[n][ho]. One thread per (n,ho,wo); weights computed once, reused for
// all 3 channels. Memory-bound: ~100 MB read, ~168 MB written.
// ---------------------------------------------------------------------------
__global__ __launch_bounds__(256) void grid_sample_kernel(
    const float* __restrict__ data, const float* __restrict__ gx,
    const float* __restrict__ gy, float* __restrict__ outS,
    float* __restrict__ outG)
{
    const int wo = blockIdx.x * 256 + threadIdx.x;
    const int ho = blockIdx.y;
    const int n  = blockIdx.z;

    const float gxv = gx[n * AN + wo];
    const float gyv = gy[n * AN + ho];

    // grid output: (N,Ho,Wo,2), channel 0 = x, channel 1 = y
    float2 g2; g2.x = gxv; g2.y = gyv;
    ((float2*)outG)[((size_t)n * HW + ho) * HW + wo] = g2;

    const float x = (gxv + 1.0f) * 256.0f - 0.5f;   // (g+1)*(W/2)-0.5
    const float y = (gyv + 1.0f) * 256.0f - 0.5f;
    const float x0f = floorf(x), y0f = floorf(y);
    const float x1f = x0f + 1.0f, y1f = y0f + 1.0f;
    const float wx1 = x - x0f, wx0 = 1.0f - wx1;
    const float wy1 = y - y0f, wy0 = 1.0f - wy1;

    const bool vx0 = (x0f >= 0.0f) && (x0f < 512.0f);
    const bool vx1 = (x1f >= 0.0f) && (x1f < 512.0f);
    const bool vy0 = (y0f >= 0.0f) && (y0f < 512.0f);
    const bool vy1 = (y1f >= 0.0f) && (y1f < 512.0f);

    const int x0 = (int)fminf(fmaxf(x0f, 0.0f), 511.0f);
    const int x1 = (int)fminf(fmaxf(x1f, 0.0f), 511.0f);
    const int y0 = (int)fminf(fmaxf(y0f, 0.0f), 511.0f);
    const int y1 = (int)fminf(fmaxf(y1f, 0.0f), 511.0f);

    const float w00 = wx0 * wy0, w10 = wx1 * wy0;
    const float w01 = wx0 * wy1, w11 = wx1 * wy1;

    const float* base = data + (size_t)n * 3 * HW * HW;
    const size_t r0 = (size_t)y0 * HW, r1 = (size_t)y1 * HW;
    size_t o = (((size_t)n * 3) * HW + ho) * HW + wo;

    #pragma unroll
    for (int c = 0; c < 3; ++c) {
        const float* p = base + (size_t)c * HW * HW;
        const float v00 = (vx0 && vy0) ? p[r0 + x0] : 0.0f;
        const float v10 = (vx1 && vy0) ? p[r0 + x1] : 0.0f;
        const float v01 = (vx0 && vy1) ? p[r1 + x0] : 0.0f;
        const float v11 = (vx1 && vy1) ? p[r1 + x1] : 0.0f;
        outS[o + (size_t)c * HW * HW] = v00 * w00 + v10 * w10 + v01 * w01 + v11 * w11;
    }
}

extern "C" void kernel_launch(void* const* d_in, const int* in_sizes, int n_in,
                              void* d_out, int out_size, void* d_ws, size_t ws_size,
                              hipStream_t stream) {
    const float* data = (const float*)d_in[0];   // (32,3,512,512)
    const float* attx = (const float*)d_in[1];   // (32,512)
    const float* atty = (const float*)d_in[2];   // (32,512)

    float* gx = (float*)d_ws;            // (32,512) width coords
    float* gy = gx + NB * AN;            // (32,512) height coords

    float* outS = (float*)d_out;                          // sampled (32,3,512,512)
    float* outG = outS + (size_t)NB * 3 * HW * HW;        // grid (32,512,512,2)

    waterfill_coords_kernel<<<NB, AN, 0, stream>>>(attx, atty, gx, gy);

    dim3 grid(HW / 256, HW, NB);
    grid_sample_kernel<<<grid, 256, 0, stream>>>(data, gx, gy, outS, outG);
}